// Round 1
// baseline (380.755 us; speedup 1.0000x reference)
//
#include <hip/hip_runtime.h>
#include <math.h>

#define BB 4
#define CC 64
#define OC 64
#define HH 128
#define WW 128
#define HP 130
#define WP 130
#define NPTS 9
#define NSLOT 18
#define KTOT (NSLOT * 64)   // 1152

// ws layout (floats):
//   xp   : [B][HP][WP][C]            = 4,326,400 floats
//   wr   : [KTOT/4][OC][4] (float4)  =    73,728 floats
//   recs : [B*H*W*9] x 5 u32         = 2,949,120 u32
#define XP_OFF 0
#define WR_OFF 4326400
#define REC_OFF (4326400 + 73728)
// total = 7,349,248 * 4B = ~29.4 MB of ws

__device__ __forceinline__ float sigmoidf_(float z) {
    return 1.f / (1.f + expf(-z));
}

__global__ void k_pad_transpose(const float* __restrict__ x, float* __restrict__ xp) {
    int idx = blockIdx.x * blockDim.x + threadIdx.x;
    int total = BB * HP * WP * CC;
    if (idx >= total) return;
    int c = idx & 63;
    int t = idx >> 6;
    int wp = t % WP; t /= WP;
    int hp = t % HP; int b = t / HP;
    float v = 0.f;
    if (hp >= 1 && hp <= HH && wp >= 1 && wp <= WW) {
        v = x[((b * CC + c) * HH + (hp - 1)) * WW + (wp - 1)];
    }
    xp[idx] = v;
}

__global__ void k_build_wr(const float* __restrict__ w_b, const float* __restrict__ w_c,
                           float* __restrict__ wr) {
    int idx = blockIdx.x * blockDim.x + threadIdx.x;   // KTOT*OC = 73728
    if (idx >= KTOT * OC) return;
    int j  = idx & 3;
    int o  = (idx >> 2) & 63;
    int k4 = idx >> 8;
    int k  = k4 * 4 + j;
    int slot = k >> 6;
    int c    = k & 63;
    float v;
    if (slot < 9) {
        v = w_b[((o * CC + c) * 3 + slot / 3) * 3 + slot % 3];
    } else {
        int n = slot - 9;
        v = w_c[((o * CC + c) * 3 + n / 3) * 3 + n % 3];
    }
    wr[idx] = v;
}

// One thread per pixel: 12-ch 3x3 conv over C=64, then build 9 sampling records.
__global__ __launch_bounds__(256) void k_offsets(
    const float* __restrict__ xp,
    const float* __restrict__ w_p, const float* __restrict__ b_p,
    const float* __restrict__ w_m, const float* __restrict__ b_m,
    unsigned int* __restrict__ recs)
{
    __shared__ float wl[9 * 64 * 12];   // [tap][c][ch], 6912 floats = 27.6KB
    int tid = threadIdx.x;
    for (int i = tid; i < 9 * 64 * 12; i += 256) {
        int ch = i % 12;
        int r  = i / 12;
        int c  = r & 63;
        int tap = r >> 6;
        int ti = tap / 3, tj = tap % 3;
        float v;
        if (ch < 3) v = w_p[((ch * CC + c) * 3 + ti) * 3 + tj];
        else        v = w_m[(((ch - 3) * CC + c) * 3 + ti) * 3 + tj];
        wl[i] = v;
    }
    __syncthreads();

    int pix = blockIdx.x * 256 + tid;            // 65536 total
    int b = pix >> 14;
    int h = (pix >> 7) & 127;
    int w = pix & 127;

    float acc[12];
#pragma unroll
    for (int i = 0; i < 12; ++i) acc[i] = 0.f;

    for (int tap = 0; tap < 9; ++tap) {
        int ti = tap / 3, tj = tap % 3;
        int base = ((b * HP + h + ti) * WP + (w + tj)) * 64;
#pragma unroll 4
        for (int c4 = 0; c4 < 16; ++c4) {
            float4 xv = *(const float4*)&xp[base + c4 * 4];
#pragma unroll
            for (int e = 0; e < 4; ++e) {
                float x1 = (e == 0) ? xv.x : (e == 1) ? xv.y : (e == 2) ? xv.z : xv.w;
                const float4* wv = (const float4*)&wl[(tap * 64 + c4 * 4 + e) * 12];
                float4 a0 = wv[0], a1 = wv[1], a2 = wv[2];
                acc[0] += x1 * a0.x;  acc[1] += x1 * a0.y;  acc[2]  += x1 * a0.z;  acc[3]  += x1 * a0.w;
                acc[4] += x1 * a1.x;  acc[5] += x1 * a1.y;  acc[6]  += x1 * a1.z;  acc[7]  += x1 * a1.w;
                acc[8] += x1 * a2.x;  acc[9] += x1 * a2.y;  acc[10] += x1 * a2.z;  acc[11] += x1 * a2.w;
            }
        }
    }

    float s0 = sigmoidf_(sinf(acc[0] + b_p[0]));
    float s1 = sigmoidf_(sinf(acc[1] + b_p[1]));
    float s2 = sigmoidf_(sinf(acc[2] + b_p[2]));
    float l     = s0 * 48.5f + 1.5f;
    float wd    = s1 * 48.5f + 1.5f;
    float theta = s2 * 3.1415926f;
    float ct = cosf(theta), st = sinf(theta);

    float px0 = (float)(h + 1);
    float py0 = (float)(w + 1);

#pragma unroll
    for (int n = 0; n < 9; ++n) {
        float mm = sigmoidf_(acc[3 + n] + b_m[n]);
        float pnx = (float)(n / 3 - 1);
        float pny = (float)(n % 3 - 1);
        float px = px0 + (l * (1.f / 3.f)) * pnx;
        float py = py0 + (wd * (1.f / 3.f)) * pny;
        float pxx = px * ct - py * st;
        float pyy = px * st + py * ct;
        float fx = floorf(pxx);
        float fy = floorf(pyy);
        int qltx = min(max((int)fx, 0), HP - 1);
        int qlty = min(max((int)fy, 0), WP - 1);
        int qrbx = min(max((int)fx + 1, 0), HP - 1);
        int qrby = min(max((int)fy + 1, 0), WP - 1);
        float pcx = fminf(fmaxf(pxx, 0.f), (float)(HP - 1));
        float pcy = fminf(fmaxf(pyy, 0.f), (float)(WP - 1));
        float dltx = 1.f + ((float)qltx - pcx);
        float drbx = 1.f - ((float)qrbx - pcx);
        float dlty = 1.f + ((float)qlty - pcy);
        float drby = 1.f - ((float)qrby - pcy);
        float g_lt = dltx * dlty * mm;
        float g_rb = drbx * drby * mm;
        float g_lb = dltx * drby * mm;
        float g_rt = drbx * dlty * mm;
        unsigned int q = (unsigned)qltx | ((unsigned)qlty << 8) |
                         ((unsigned)qrbx << 16) | ((unsigned)qrby << 24);
        unsigned int* r = &recs[(size_t)(pix * 9 + n) * 5];
        r[0] = q;
        r[1] = __float_as_uint(g_lt);
        r[2] = __float_as_uint(g_rb);
        r[3] = __float_as_uint(g_lb);
        r[4] = __float_as_uint(g_rt);
    }
}

// Main: per 8-pixel tile build U[8][1152] in LDS, then GEMV per (o, pixel).
__global__ __launch_bounds__(256) void k_main(
    const float* __restrict__ xp, const float* __restrict__ wr,
    const unsigned int* __restrict__ recs, const float* __restrict__ b_b,
    float* __restrict__ out)
{
    __shared__ float U[8][KTOT];   // 36,864 B
    int tid = threadIdx.x;
    int c = tid & 63;
    int g = tid >> 6;              // wave id 0..3
    int tileBase = blockIdx.x * 8; // linear pixel base; all 8 share (b, h)

#pragma unroll
    for (int pp = 0; pp < 2; ++pp) {
        int p = g * 2 + pp;
        int pix = tileBase + p;
        int b = pix >> 14;
        int h = (pix >> 7) & 127;
        int w = pix & 127;
        const float* xb = xp + (size_t)b * HP * WP * 64;
        // fixed 3x3 taps (bias-conv operand)
#pragma unroll
        for (int tap = 0; tap < 9; ++tap) {
            int ti = tap / 3, tj = tap % 3;
            U[p][tap * 64 + c] = xb[((h + ti) * WP + (w + tj)) * 64 + c];
        }
        // deformable samples
#pragma unroll
        for (int n = 0; n < 9; ++n) {
            const unsigned int* r = &recs[(size_t)(pix * 9 + n) * 5];
            unsigned int q = r[0];
            float g_lt = __uint_as_float(r[1]);
            float g_rb = __uint_as_float(r[2]);
            float g_lb = __uint_as_float(r[3]);
            float g_rt = __uint_as_float(r[4]);
            int qltx = q & 255, qlty = (q >> 8) & 255;
            int qrbx = (q >> 16) & 255, qrby = (q >> 24) & 255;
            float xlt = xb[(qltx * WP + qlty) * 64 + c];
            float xrb = xb[(qrbx * WP + qrby) * 64 + c];
            float xlb = xb[(qltx * WP + qrby) * 64 + c];
            float xrt = xb[(qrbx * WP + qlty) * 64 + c];
            U[p][(9 + n) * 64 + c] = g_lt * xlt + g_rb * xrb + g_lb * xlb + g_rt * xrt;
        }
    }
    __syncthreads();

    // GEMV: thread (o = tid&63) handles pixels p0,p1 = 2*g, 2*g+1
    int o = c;
    int p0 = g * 2, p1 = g * 2 + 1;
    float acc0 = 0.f, acc1 = 0.f;
    const float4* wr4 = (const float4*)wr;
#pragma unroll 4
    for (int k4 = 0; k4 < KTOT / 4; ++k4) {
        float4 wv = wr4[k4 * 64 + o];
        float4 u0 = *(const float4*)&U[p0][k4 * 4];
        float4 u1 = *(const float4*)&U[p1][k4 * 4];
        acc0 += wv.x * u0.x + wv.y * u0.y + wv.z * u0.z + wv.w * u0.w;
        acc1 += wv.x * u1.x + wv.y * u1.y + wv.z * u1.z + wv.w * u1.w;
    }
    float bias = b_b[o];
    int pix0 = tileBase + p0;
    int b0 = pix0 >> 14;
    int hw0 = pix0 & 16383;
    out[((size_t)b0 * 64 + o) * 16384 + hw0]     = acc0 + bias;
    out[((size_t)b0 * 64 + o) * 16384 + hw0 + 1] = acc1 + bias;
}

extern "C" void kernel_launch(void* const* d_in, const int* in_sizes, int n_in,
                              void* d_out, int out_size, void* d_ws, size_t ws_size,
                              hipStream_t stream) {
    const float* x   = (const float*)d_in[0];
    const float* w_b = (const float*)d_in[1];
    const float* b_b = (const float*)d_in[2];
    const float* w_p = (const float*)d_in[3];
    const float* b_p = (const float*)d_in[4];
    const float* w_m = (const float*)d_in[5];
    const float* b_m = (const float*)d_in[6];
    const float* w_c = (const float*)d_in[7];
    float* out = (float*)d_out;

    float* ws = (float*)d_ws;
    float* xp = ws + XP_OFF;
    float* wr = ws + WR_OFF;
    unsigned int* recs = (unsigned int*)(ws + REC_OFF);

    {
        int total = BB * HP * WP * CC;
        k_pad_transpose<<<(total + 255) / 256, 256, 0, stream>>>(x, xp);
    }
    k_build_wr<<<(KTOT * OC + 255) / 256, 256, 0, stream>>>(w_b, w_c, wr);
    k_offsets<<<(BB * HH * WW) / 256, 256, 0, stream>>>(xp, w_p, b_p, w_m, b_m, recs);
    k_main<<<(BB * HH * WW) / 8, 256, 0, stream>>>(xp, wr, recs, b_b, out);
}

// Round 2
// 124.591 us; speedup vs baseline: 3.0560x; 3.0560x over previous
//
#include <hip/hip_runtime.h>
#include <math.h>

#define BB 4
#define CC 64
#define OC 64
#define HH 128
#define WW 128
#define HP 130
#define WP 130
#define NSLOT 18
#define KTOT (NSLOT * 64)   // 1152
#define NKK (KTOT / 32)     // 36 MFMA K-steps

// ws layout (float units):
//   xp   : [B][HP][WP][C]              = 4,326,400 floats
//   recs : [B*H*W*9] x 5 u32           = 2,949,120 u32
//   wr8  : [36][4][64][8] bf16         = 73,728 ushort = 36,864 float slots
#define XP_OFF 0
#define REC_OFF 4326400
#define WR8_OFF (4326400 + 2949120)

typedef __attribute__((ext_vector_type(8))) short bf16x8;
typedef __attribute__((ext_vector_type(4))) short bf16x4;
typedef __attribute__((ext_vector_type(4))) float f32x4;

__device__ __forceinline__ float sigmoidf_(float z) {
    return 1.f / (1.f + expf(-z));
}

__device__ __forceinline__ unsigned short f2bf(float v) {
    union { float f; unsigned int u; } x; x.f = v;
    unsigned int r = x.u + 0x7FFF + ((x.u >> 16) & 1);   // RNE
    return (unsigned short)(r >> 16);
}

__global__ void k_pad_transpose(const float* __restrict__ x, float* __restrict__ xp) {
    int idx = blockIdx.x * blockDim.x + threadIdx.x;
    int total = BB * HP * WP * CC;
    if (idx >= total) return;
    int c = idx & 63;
    int t = idx >> 6;
    int wp = t % WP; t /= WP;
    int hp = t % HP; int b = t / HP;
    float v = 0.f;
    if (hp >= 1 && hp <= HH && wp >= 1 && wp <= WW) {
        v = x[((b * CC + c) * HH + (hp - 1)) * WW + (wp - 1)];
    }
    xp[idx] = v;
}

// Pack W = [w_b | w_c] into exact MFMA A-fragment order, bf16:
// wr8[kk][ot][lane][j] = W[o = ot*16 + (lane&15)][k = kk*32 + (lane>>4)*8 + j]
__global__ void k_build_wr8(const float* __restrict__ w_b, const float* __restrict__ w_c,
                            unsigned short* __restrict__ wr8) {
    int idx = blockIdx.x * blockDim.x + threadIdx.x;   // 73728
    if (idx >= NKK * 4 * 64 * 8) return;
    int j    = idx & 7;
    int lane = (idx >> 3) & 63;
    int ot   = (idx >> 9) & 3;
    int kk   = idx >> 11;
    int m  = lane & 15, kq = lane >> 4;
    int o  = ot * 16 + m;
    int k  = kk * 32 + kq * 8 + j;
    int slot = k >> 6;
    int c    = k & 63;
    float v;
    if (slot < 9) {
        v = w_b[((o * CC + c) * 3 + slot / 3) * 3 + slot % 3];
    } else {
        int n = slot - 9;
        v = w_c[((o * CC + c) * 3 + n / 3) * 3 + n % 3];
    }
    wr8[idx] = f2bf(v);
}

// One thread per pixel: 12-ch 3x3 conv over C=64 (f32 — position precision),
// then build 9 sampling records.
__global__ __launch_bounds__(256) void k_offsets(
    const float* __restrict__ xp,
    const float* __restrict__ w_p, const float* __restrict__ b_p,
    const float* __restrict__ w_m, const float* __restrict__ b_m,
    unsigned int* __restrict__ recs)
{
    __shared__ float wl[9 * 64 * 12];   // [tap][c][ch]
    int tid = threadIdx.x;
    for (int i = tid; i < 9 * 64 * 12; i += 256) {
        int ch = i % 12;
        int r  = i / 12;
        int c  = r & 63;
        int tap = r >> 6;
        int ti = tap / 3, tj = tap % 3;
        float v;
        if (ch < 3) v = w_p[((ch * CC + c) * 3 + ti) * 3 + tj];
        else        v = w_m[(((ch - 3) * CC + c) * 3 + ti) * 3 + tj];
        wl[i] = v;
    }
    __syncthreads();

    int pix = blockIdx.x * 256 + tid;
    int b = pix >> 14;
    int h = (pix >> 7) & 127;
    int w = pix & 127;

    float acc[12];
#pragma unroll
    for (int i = 0; i < 12; ++i) acc[i] = 0.f;

    for (int tap = 0; tap < 9; ++tap) {
        int ti = tap / 3, tj = tap % 3;
        int base = ((b * HP + h + ti) * WP + (w + tj)) * 64;
#pragma unroll 4
        for (int c4 = 0; c4 < 16; ++c4) {
            float4 xv = *(const float4*)&xp[base + c4 * 4];
#pragma unroll
            for (int e = 0; e < 4; ++e) {
                float x1 = (e == 0) ? xv.x : (e == 1) ? xv.y : (e == 2) ? xv.z : xv.w;
                const float4* wv = (const float4*)&wl[(tap * 64 + c4 * 4 + e) * 12];
                float4 a0 = wv[0], a1 = wv[1], a2 = wv[2];
                acc[0] += x1 * a0.x;  acc[1] += x1 * a0.y;  acc[2]  += x1 * a0.z;  acc[3]  += x1 * a0.w;
                acc[4] += x1 * a1.x;  acc[5] += x1 * a1.y;  acc[6]  += x1 * a1.z;  acc[7]  += x1 * a1.w;
                acc[8] += x1 * a2.x;  acc[9] += x1 * a2.y;  acc[10] += x1 * a2.z;  acc[11] += x1 * a2.w;
            }
        }
    }

    float s0 = sigmoidf_(sinf(acc[0] + b_p[0]));
    float s1 = sigmoidf_(sinf(acc[1] + b_p[1]));
    float s2 = sigmoidf_(sinf(acc[2] + b_p[2]));
    float l     = s0 * 48.5f + 1.5f;
    float wd    = s1 * 48.5f + 1.5f;
    float theta = s2 * 3.1415926f;
    float ct = cosf(theta), st = sinf(theta);

    float px0 = (float)(h + 1);
    float py0 = (float)(w + 1);

#pragma unroll
    for (int n = 0; n < 9; ++n) {
        float mm = sigmoidf_(acc[3 + n] + b_m[n]);
        float pnx = (float)(n / 3 - 1);
        float pny = (float)(n % 3 - 1);
        float px = px0 + (l * (1.f / 3.f)) * pnx;
        float py = py0 + (wd * (1.f / 3.f)) * pny;
        float pxx = px * ct - py * st;
        float pyy = px * st + py * ct;
        float fx = floorf(pxx);
        float fy = floorf(pyy);
        int qltx = min(max((int)fx, 0), HP - 1);
        int qlty = min(max((int)fy, 0), WP - 1);
        int qrbx = min(max((int)fx + 1, 0), HP - 1);
        int qrby = min(max((int)fy + 1, 0), WP - 1);
        float pcx = fminf(fmaxf(pxx, 0.f), (float)(HP - 1));
        float pcy = fminf(fmaxf(pyy, 0.f), (float)(WP - 1));
        float dltx = 1.f + ((float)qltx - pcx);
        float drbx = 1.f - ((float)qrbx - pcx);
        float dlty = 1.f + ((float)qlty - pcy);
        float drby = 1.f - ((float)qrby - pcy);
        float g_lt = dltx * dlty * mm;
        float g_rb = drbx * drby * mm;
        float g_lb = dltx * drby * mm;
        float g_rt = drbx * dlty * mm;
        unsigned int q = (unsigned)qltx | ((unsigned)qlty << 8) |
                         ((unsigned)qrbx << 16) | ((unsigned)qrby << 24);
        unsigned int* r = &recs[(size_t)(pix * 9 + n) * 5];
        r[0] = q;
        r[1] = __float_as_uint(g_lt);
        r[2] = __float_as_uint(g_rb);
        r[3] = __float_as_uint(g_lb);
        r[4] = __float_as_uint(g_rt);
    }
}

// Main: 16-pixel tile. Phase 1: build U[1152][16] in LDS (bf16, XOR-swizzled
// 16B blocks). Phase 2: 4 waves x (16o x 16pix) MFMA over K=1152.
// U element (k, p) lives at 16B-block blk = (k>>3)*16 + (p ^ ((k>>3)&15)),
// byte (k&7)*2 — writes spread across all 32 banks, reads conflict-free b128.
__global__ __launch_bounds__(256) void k_main(
    const float* __restrict__ xp, const unsigned short* __restrict__ wr8,
    const unsigned int* __restrict__ recs, const float* __restrict__ b_b,
    float* __restrict__ out)
{
    __shared__ unsigned short U8[2304 * 8];   // 36,864 B
    int tid = threadIdx.x;
    int lane = tid & 63;
    int g = tid >> 6;
    int pixBase = blockIdx.x * 16;

    // ---- phase 1: each wave builds 4 pixels; lane = (p_local&3)*16 + cq
    {
        int p_local = g * 4 + (lane >> 4);   // 0..15
        int cq = lane & 15;
        int c0 = cq * 4;
        int pix = pixBase + p_local;
        int b = pix >> 14;
        int h = (pix >> 7) & 127;
        int w = pix & 127;
        const float* xb = xp + (size_t)b * HP * WP * 64;

        // fixed 3x3 taps (slots 0..8)
#pragma unroll
        for (int tap = 0; tap < 9; ++tap) {
            int ti = tap / 3, tj = tap % 3;
            float4 xv = *(const float4*)&xb[((h + ti) * WP + (w + tj)) * 64 + c0];
            int k = tap * 64 + c0;
            int kqt = k >> 3;
            int blk = kqt * 16 + (p_local ^ (kqt & 15));
            bf16x4 pk;
            pk[0] = (short)f2bf(xv.x); pk[1] = (short)f2bf(xv.y);
            pk[2] = (short)f2bf(xv.z); pk[3] = (short)f2bf(xv.w);
            *(bf16x4*)&U8[blk * 8 + (k & 7)] = pk;
        }
        // deformable samples (slots 9..17)
#pragma unroll
        for (int n = 0; n < 9; ++n) {
            const unsigned int* r = &recs[(size_t)(pix * 9 + n) * 5];
            unsigned int q = r[0];
            float g_lt = __uint_as_float(r[1]);
            float g_rb = __uint_as_float(r[2]);
            float g_lb = __uint_as_float(r[3]);
            float g_rt = __uint_as_float(r[4]);
            int qltx = q & 255, qlty = (q >> 8) & 255;
            int qrbx = (q >> 16) & 255, qrby = (q >> 24) & 255;
            float4 xlt = *(const float4*)&xb[(qltx * WP + qlty) * 64 + c0];
            float4 xrb = *(const float4*)&xb[(qrbx * WP + qrby) * 64 + c0];
            float4 xlb = *(const float4*)&xb[(qltx * WP + qrby) * 64 + c0];
            float4 xrt = *(const float4*)&xb[(qrbx * WP + qlty) * 64 + c0];
            float v0 = g_lt * xlt.x + g_rb * xrb.x + g_lb * xlb.x + g_rt * xrt.x;
            float v1 = g_lt * xlt.y + g_rb * xrb.y + g_lb * xlb.y + g_rt * xrt.y;
            float v2 = g_lt * xlt.z + g_rb * xrb.z + g_lb * xlb.z + g_rt * xrt.z;
            float v3 = g_lt * xlt.w + g_rb * xrb.w + g_lb * xlb.w + g_rt * xrt.w;
            int k = (9 + n) * 64 + c0;
            int kqt = k >> 3;
            int blk = kqt * 16 + (p_local ^ (kqt & 15));
            bf16x4 pk;
            pk[0] = (short)f2bf(v0); pk[1] = (short)f2bf(v1);
            pk[2] = (short)f2bf(v2); pk[3] = (short)f2bf(v3);
            *(bf16x4*)&U8[blk * 8 + (k & 7)] = pk;
        }
    }
    __syncthreads();

    // ---- phase 2: wave g computes o-tile g (16 outputs) x 16 pixels
    int ot = g;
    f32x4 acc0 = {0.f, 0.f, 0.f, 0.f}, acc1 = {0.f, 0.f, 0.f, 0.f};
    const bf16x8* wv = (const bf16x8*)wr8;
    int kq = lane >> 4;
    int pn = lane & 15;
#pragma unroll
    for (int kk = 0; kk < NKK; ++kk) {
        bf16x8 a = wv[(kk * 4 + ot) * 64 + lane];
        int kqt = kk * 4 + kq;
        int blk = kqt * 16 + (pn ^ (kqt & 15));
        bf16x8 bfr = *(const bf16x8*)&U8[blk * 8];
        if (kk & 1) acc1 = __builtin_amdgcn_mfma_f32_16x16x32_bf16(a, bfr, acc1, 0, 0, 0);
        else        acc0 = __builtin_amdgcn_mfma_f32_16x16x32_bf16(a, bfr, acc0, 0, 0, 0);
    }

    // epilogue: D row = o_sub = (lane>>4)*4 + r2, col = pixel = lane&15
    int row0 = (lane >> 4) * 4;
    int hw = (pixBase & 16383) + pn;
    int bb = pixBase >> 14;
#pragma unroll
    for (int r2 = 0; r2 < 4; ++r2) {
        int o = ot * 16 + row0 + r2;
        out[((size_t)(bb * 64 + o)) * 16384 + hw] = acc0[r2] + acc1[r2] + b_b[o];
    }
}

extern "C" void kernel_launch(void* const* d_in, const int* in_sizes, int n_in,
                              void* d_out, int out_size, void* d_ws, size_t ws_size,
                              hipStream_t stream) {
    const float* x   = (const float*)d_in[0];
    const float* w_b = (const float*)d_in[1];
    const float* b_b = (const float*)d_in[2];
    const float* w_p = (const float*)d_in[3];
    const float* b_p = (const float*)d_in[4];
    const float* w_m = (const float*)d_in[5];
    const float* b_m = (const float*)d_in[6];
    const float* w_c = (const float*)d_in[7];
    float* out = (float*)d_out;

    float* ws = (float*)d_ws;
    float* xp = ws + XP_OFF;
    unsigned int* recs = (unsigned int*)(ws + REC_OFF);
    unsigned short* wr8 = (unsigned short*)(ws + WR8_OFF);

    {
        int total = BB * HP * WP * CC;
        k_pad_transpose<<<(total + 255) / 256, 256, 0, stream>>>(x, xp);
    }
    k_build_wr8<<<(NKK * 4 * 64 * 8 + 255) / 256, 256, 0, stream>>>(w_b, w_c, wr8);
    k_offsets<<<(BB * HH * WW) / 256, 256, 0, stream>>>(xp, w_p, b_p, w_m, b_m, recs);
    k_main<<<(BB * HH * WW) / 16, 256, 0, stream>>>(xp, wr8, recs, b_b, out);
}

// Round 4
// 79.547 us; speedup vs baseline: 4.7865x; 1.5663x over previous
//
#include <hip/hip_runtime.h>
#include <math.h>

#define BB 4
#define CC 64
#define OC 64
#define HH 128
#define WW 128
#define HP 130
#define WP 130
#define KTOT 1152           // 18 slots * 64 ch
#define NKK 36              // main GEMM K-steps (K=32 each)
#define NKC 18              // offset-conv K-steps (K=576)
#define PIXT 32             // pixels per k_main block

// ws layout (float units):
//   xp   : [B][HP][WP][C] f32   = 4,326,400 floats
//   wr8  : [36][4][64][8] bf16  = 73,728 ushort (36,864 float slots)
//   wpm8 : [18][64][8]   bf16   =  9,216 ushort ( 4,608 float slots)
#define XP_OFF 0
#define WR8_OFF 4326400
#define WPM8_OFF (4326400 + 36864)

typedef __attribute__((ext_vector_type(8))) short bf16x8;
typedef __attribute__((ext_vector_type(4))) short bf16x4;
typedef __attribute__((ext_vector_type(4))) float f32x4;

__device__ __forceinline__ float sigmoidf_(float z) {
    return 1.f / (1.f + expf(-z));
}
__device__ __forceinline__ unsigned short f2bf(float v) {
    union { float f; unsigned int u; } x; x.f = v;
    unsigned int r = x.u + 0x7FFF + ((x.u >> 16) & 1);   // RNE
    return (unsigned short)(r >> 16);
}

// ---------------- k_prep: pad-transpose + border zero + weight packs ----------------
#define NB_TR 1024   // 4 b * 128 h * 2 wtiles
#define NB_BZ 516    // 4*516*64/256
#define NB_WR 288    // 73728/256
#define NB_WPM 36    // 9216/256

__global__ __launch_bounds__(256) void k_prep(
    const float* __restrict__ x,
    const float* __restrict__ w_b, const float* __restrict__ w_c,
    const float* __restrict__ w_p, const float* __restrict__ w_m,
    float* __restrict__ xp, unsigned short* __restrict__ wr8,
    unsigned short* __restrict__ wpm8)
{
    int bi = blockIdx.x;
    int tid = threadIdx.x;
    if (bi < NB_TR) {
        // transpose one (b, h, 64-wide w tile): x[b,c,h,w] -> xp[b,h+1,w+1,c]
        __shared__ float t[64][65];
        int b = bi >> 8;
        int h = (bi >> 1) & 127;
        int w0 = (bi & 1) * 64;
        int lane6 = tid & 63;
        for (int cc = tid >> 6; cc < 64; cc += 4)
            t[cc][lane6] = x[((b * 64 + cc) * 128 + h) * 128 + w0 + lane6];
        __syncthreads();
        for (int wsub = tid >> 6; wsub < 64; wsub += 4)
            xp[((size_t)(b * HP + h + 1) * WP + (w0 + wsub + 1)) * 64 + lane6] = t[lane6][wsub];
        return;
    }
    bi -= NB_TR;
    if (bi < NB_BZ) {
        // zero the padded border of xp
        int idx = bi * 256 + tid;            // < 4*516*64
        int c = idx & 63;
        int tt = idx >> 6;                   // 0..2063
        int b = tt / 516;
        int j = tt % 516;
        int hp, wp;
        if (j < 130)      { hp = 0;       wp = j; }
        else if (j < 260) { hp = 129;     wp = j - 130; }
        else if (j < 388) { hp = j - 259; wp = 0; }
        else              { hp = j - 387; wp = 129; }
        xp[((size_t)(b * HP + hp) * WP + wp) * 64 + c] = 0.f;
        return;
    }
    bi -= NB_BZ;
    if (bi < NB_WR) {
        // main-GEMM A pack: wr8[kk][ot][lane][j] = W[o=ot*16+(lane&15)][k=kk*32+(lane>>4)*8+j]
        int idx = bi * 256 + tid;            // < 73728
        int j    = idx & 7;
        int lane = (idx >> 3) & 63;
        int ot   = (idx >> 9) & 3;
        int kk   = idx >> 11;
        int o  = ot * 16 + (lane & 15);
        int k  = kk * 32 + (lane >> 4) * 8 + j;
        int slot = k >> 6;
        int c    = k & 63;
        float v;
        if (slot < 9) v = w_b[((o * CC + c) * 3 + slot / 3) * 3 + slot % 3];
        else { int n = slot - 9; v = w_c[((o * CC + c) * 3 + n / 3) * 3 + n % 3]; }
        wr8[idx] = f2bf(v);
        return;
    }
    bi -= NB_WR;
    {
        // offset/mask-conv A pack: wpm8[kk][lane][j] = Wpm[ch=lane&15][k=kk*32+(lane>>4)*8+j]
        int idx = bi * 256 + tid;            // < 9216
        if (idx >= NKC * 64 * 8) return;
        int j    = idx & 7;
        int lane = (idx >> 3) & 63;
        int kk   = idx >> 9;                 // 0..17
        int ch = lane & 15;
        int k  = kk * 32 + (lane >> 4) * 8 + j;   // 0..575
        int tap = k >> 6;
        int c   = k & 63;
        float v = 0.f;
        if (ch < 3)       v = w_p[((ch * CC + c) * 3 + tap / 3) * 3 + tap % 3];
        else if (ch < 12) v = w_m[(((ch - 3) * CC + c) * 3 + tap / 3) * 3 + tap % 3];
        wpm8[idx] = f2bf(v);
    }
}

// ---------------- k_main: fused offsets + gather + dual GEMM ----------------
// 512 threads = 8 waves, 32 pixels/block.
// LDS U: two 16-pixel halves; element (k, p16) at 16B-block blk=(k>>3)*16+(p16^((k>>3)&15)),
// ushort offset within block = k&7. Writes spread banks; b128 reads conflict-free
// (measured 0 conflicts in rounds 1-2 with this layout).
__global__ __launch_bounds__(512, 4) void k_main(
    const float* __restrict__ xp, const unsigned short* __restrict__ wr8,
    const unsigned short* __restrict__ wpm8,
    const float* __restrict__ w_p,
    const float* __restrict__ b_p, const float* __restrict__ b_m,
    const float* __restrict__ b_b, float* __restrict__ out)
{
    __shared__ unsigned short U8[2 * 18432];   // 73,728 B
    __shared__ float wth[16][9][4];            // f32 theta-channel weights: [cq][tap][e]

    int tid = threadIdx.x;
    int lane = tid & 63;
    int g = tid >> 6;                 // wave 0..7
    int p_sub = lane >> 4;            // 0..3
    int cq = lane & 15;
    int c0 = cq * 4;

    // XCD-aware swizzle (2048 blocks, divisible by 8)
    int bid = blockIdx.x;
    int swz = (bid & 7) * 256 + (bid >> 3);
    int pixBase = swz * PIXT;

    // fill theta-weight table: wth[cq][tap][e] = w_p[ch=2][c=cq*4+e][tap/3][tap%3]
    // 576 entries, 512 threads -> stride loop (round-3 bug: tail was unfilled)
    for (int i = tid; i < 576; i += 512) {
        int cqi = i / 36;
        int rest = i % 36;
        int tap = rest >> 2;
        int e = rest & 3;
        int c = cqi * 4 + e;
        wth[cqi][tap][e] = w_p[((2 * CC + c) * 3 + tap / 3) * 3 + tap % 3];
    }
    __syncthreads();

    int p_local = g * 4 + p_sub;                 // 0..31
    int ph = p_local >> 4;
    int p16 = p_local & 15;
    int pix = pixBase + p_local;
    int b = pix >> 14;
    int h = (pix >> 7) & 127;
    int w = pix & 127;
    const float* xb = xp + (size_t)b * HP * WP * 64;

    // ---- phase 1a: fixed taps -> U slots 0..8 (bf16) + f32 theta partial
    float th = 0.f;
#pragma unroll
    for (int tap = 0; tap < 9; ++tap) {
        int ti = tap / 3, tj = tap % 3;
        float4 xv = *(const float4*)&xb[((h + ti) * WP + (w + tj)) * 64 + c0];
        float4 wt = *(const float4*)&wth[cq][tap][0];
        th += xv.x * wt.x + xv.y * wt.y + xv.z * wt.z + xv.w * wt.w;
        int k = tap * 64 + c0;
        int kqt = k >> 3;
        int blk = kqt * 16 + (p16 ^ (kqt & 15));
        bf16x4 pk;
        pk[0] = (short)f2bf(xv.x); pk[1] = (short)f2bf(xv.y);
        pk[2] = (short)f2bf(xv.z); pk[3] = (short)f2bf(xv.w);
        *(bf16x4*)&U8[ph * 18432 + blk * 8 + (k & 7)] = pk;
    }
    // reduce theta over the 16 lanes (cq) of the pixel-group
    th += __shfl_xor(th, 1);
    th += __shfl_xor(th, 2);
    th += __shfl_xor(th, 4);
    th += __shfl_xor(th, 8);
    __syncthreads();

    // ---- phase 1b: 12-ch offset/mask conv via MFMA on this wave's own 4 pixels.
    // B-cols replicate the 4 pixels x4 (same-address LDS broadcast, free).
    int kq = lane >> 4;
    f32x4 ca = {0.f, 0.f, 0.f, 0.f}, cb = {0.f, 0.f, 0.f, 0.f};
    {
        int colp = lane & 3;
        int pabs = g * 4 + colp;
        int phc = g >> 2;
        int p16c = pabs & 15;
        const bf16x8* av = (const bf16x8*)wpm8;
#pragma unroll
        for (int kk = 0; kk < NKC; ++kk) {
            bf16x8 a = av[kk * 64 + lane];
            int kqt = kk * 4 + kq;
            int blk = kqt * 16 + (p16c ^ (kqt & 15));
            bf16x8 bf = *(const bf16x8*)&U8[phc * 18432 + blk * 8];
            if (kk & 1) cb = __builtin_amdgcn_mfma_f32_16x16x32_bf16(a, bf, cb, 0, 0, 0);
            else        ca = __builtin_amdgcn_mfma_f32_16x16x32_bf16(a, bf, ca, 0, 0, 0);
        }
        ca[0] += cb[0]; ca[1] += cb[1]; ca[2] += cb[2]; ca[3] += cb[3];
    }
    // redistribute conv D (row=ch=(lane>>4)*4+reg, col) to all lanes:
    // value for (ch, my pixel p_sub) lives in lane (ch>>2)*16 + p_sub, reg ch&3.
    float conv[12];
#pragma unroll
    for (int ch = 0; ch < 12; ++ch) {
        conv[ch] = __shfl(ca[ch & 3], ((ch >> 2) << 4) + p_sub);
    }

    // ---- record math (redundant across the 16 lanes of a pixel-group)
    float l  = sigmoidf_(sinf(conv[0] + b_p[0])) * 48.5f + 1.5f;
    float wd = sigmoidf_(sinf(conv[1] + b_p[1])) * 48.5f + 1.5f;
    float theta = sigmoidf_(sinf(th + b_p[2])) * 3.1415926f;
    float ct = cosf(theta), st = sinf(theta);
    float px0 = (float)(h + 1);
    float py0 = (float)(w + 1);

    // ---- phase 1c: deformable gathers -> U slots 9..17
#pragma unroll
    for (int n = 0; n < 9; ++n) {
        float mm = sigmoidf_(conv[3 + n] + b_m[n]);
        float pnx = (float)(n / 3 - 1);
        float pny = (float)(n % 3 - 1);
        float px = px0 + (l * (1.f / 3.f)) * pnx;
        float py = py0 + (wd * (1.f / 3.f)) * pny;
        float pxx = px * ct - py * st;
        float pyy = px * st + py * ct;
        float fx = floorf(pxx);
        float fy = floorf(pyy);
        int qltx = min(max((int)fx, 0), HP - 1);
        int qlty = min(max((int)fy, 0), WP - 1);
        int qrbx = min(max((int)fx + 1, 0), HP - 1);
        int qrby = min(max((int)fy + 1, 0), WP - 1);
        float pcx = fminf(fmaxf(pxx, 0.f), (float)(HP - 1));
        float pcy = fminf(fmaxf(pyy, 0.f), (float)(WP - 1));
        float dltx = 1.f + ((float)qltx - pcx);
        float drbx = 1.f - ((float)qrbx - pcx);
        float dlty = 1.f + ((float)qlty - pcy);
        float drby = 1.f - ((float)qrby - pcy);
        float g_lt = dltx * dlty * mm;
        float g_rb = drbx * drby * mm;
        float g_lb = dltx * drby * mm;
        float g_rt = drbx * dlty * mm;
        float4 xlt = *(const float4*)&xb[(qltx * WP + qlty) * 64 + c0];
        float4 xrb = *(const float4*)&xb[(qrbx * WP + qrby) * 64 + c0];
        float4 xlb = *(const float4*)&xb[(qltx * WP + qrby) * 64 + c0];
        float4 xrt = *(const float4*)&xb[(qrbx * WP + qlty) * 64 + c0];
        float v0 = g_lt * xlt.x + g_rb * xrb.x + g_lb * xlb.x + g_rt * xrt.x;
        float v1 = g_lt * xlt.y + g_rb * xrb.y + g_lb * xlb.y + g_rt * xrt.y;
        float v2 = g_lt * xlt.z + g_rb * xrb.z + g_lb * xlb.z + g_rt * xrt.z;
        float v3 = g_lt * xlt.w + g_rb * xrb.w + g_lb * xlb.w + g_rt * xrt.w;
        int k = (9 + n) * 64 + c0;
        int kqt = k >> 3;
        int blk = kqt * 16 + (p16 ^ (kqt & 15));
        bf16x4 pk;
        pk[0] = (short)f2bf(v0); pk[1] = (short)f2bf(v1);
        pk[2] = (short)f2bf(v2); pk[3] = (short)f2bf(v3);
        *(bf16x4*)&U8[ph * 18432 + blk * 8 + (k & 7)] = pk;
    }
    __syncthreads();

    // ---- phase 2: main GEMM, wave (ot=g&3, ph2=g>>2): 16 o x 16 pixels, K=1152
    int ot = g & 3;
    int ph2 = g >> 2;
    int pn = lane & 15;
    f32x4 a0 = {0.f, 0.f, 0.f, 0.f}, a1 = {0.f, 0.f, 0.f, 0.f};
    const bf16x8* wv = (const bf16x8*)wr8;
#pragma unroll
    for (int kk = 0; kk < NKK; ++kk) {
        bf16x8 a = wv[(kk * 4 + ot) * 64 + lane];
        int kqt = kk * 4 + kq;
        int blk = kqt * 16 + (pn ^ (kqt & 15));
        bf16x8 bf = *(const bf16x8*)&U8[ph2 * 18432 + blk * 8];
        if (kk & 1) a1 = __builtin_amdgcn_mfma_f32_16x16x32_bf16(a, bf, a1, 0, 0, 0);
        else        a0 = __builtin_amdgcn_mfma_f32_16x16x32_bf16(a, bf, a0, 0, 0, 0);
    }

    int pix2 = pixBase + ph2 * 16 + pn;
    int bb2 = pix2 >> 14;
    int hw = pix2 & 16383;
#pragma unroll
    for (int r2 = 0; r2 < 4; ++r2) {
        int o = ot * 16 + kq * 4 + r2;
        out[((size_t)(bb2 * 64 + o)) * 16384 + hw] = a0[r2] + a1[r2] + b_b[o];
    }
}

extern "C" void kernel_launch(void* const* d_in, const int* in_sizes, int n_in,
                              void* d_out, int out_size, void* d_ws, size_t ws_size,
                              hipStream_t stream) {
    const float* x   = (const float*)d_in[0];
    const float* w_b = (const float*)d_in[1];
    const float* b_b = (const float*)d_in[2];
    const float* w_p = (const float*)d_in[3];
    const float* b_p = (const float*)d_in[4];
    const float* w_m = (const float*)d_in[5];
    const float* b_m = (const float*)d_in[6];
    const float* w_c = (const float*)d_in[7];
    float* out = (float*)d_out;

    float* ws = (float*)d_ws;
    float* xp = ws + XP_OFF;
    unsigned short* wr8  = (unsigned short*)(ws + WR8_OFF);
    unsigned short* wpm8 = (unsigned short*)(ws + WPM8_OFF);

    k_prep<<<NB_TR + NB_BZ + NB_WR + NB_WPM, 256, 0, stream>>>(
        x, w_b, w_c, w_p, w_m, xp, wr8, wpm8);
    k_main<<<(BB * HH * WW) / PIXT, 512, 0, stream>>>(
        xp, wr8, wpm8, w_p, b_p, b_m, b_b, out);
}

// Round 5
// 71.750 us; speedup vs baseline: 5.3067x; 1.1087x over previous
//
#include <hip/hip_runtime.h>
#include <math.h>

#define BB 4
#define CC 64
#define OC 64
#define HH 128
#define WW 128
#define HP 130
#define WP 130
#define KTOT 1152           // 18 slots * 64 ch
#define NKK 36              // main GEMM K-steps (K=32 each)
#define NKC 18              // offset-conv K-steps (K=576)
#define PIXT 32             // pixels per k_main block

// ws layout (float units):
//   xp   : [B][HP][WP][C] f32   = 4,326,400 floats
//   wr8  : [36][4][64][8] bf16  = 73,728 ushort (36,864 float slots)
//   wpm8 : [18][64][8]   bf16   =  9,216 ushort ( 4,608 float slots)
#define XP_OFF 0
#define WR8_OFF 4326400
#define WPM8_OFF (4326400 + 36864)

typedef __attribute__((ext_vector_type(8))) short bf16x8;
typedef __attribute__((ext_vector_type(4))) short bf16x4;
typedef __attribute__((ext_vector_type(4))) float f32x4;

__device__ __forceinline__ unsigned short f2bf(float v) {
    union { float f; unsigned int u; } x; x.f = v;
    unsigned int r = x.u + 0x7FFF + ((x.u >> 16) & 1);   // RNE
    return (unsigned short)(r >> 16);
}

// fast transcendentals: v_exp/v_sin/v_cos (+fract pre-reduction, cdna4_isa §3)
__device__ __forceinline__ float fexp_(float x) {          // e^x
    return __builtin_amdgcn_exp2f(x * 1.44269504089f);
}
__device__ __forceinline__ float fsig_(float z) {          // sigmoid
    return __builtin_amdgcn_rcpf(1.f + fexp_(-z));
}
__device__ __forceinline__ float fsin_(float x) {          // sin, radians
    float r = x * 0.15915494309f;
    r = __builtin_amdgcn_fractf(r);
    return __builtin_amdgcn_sinf(r);
}
__device__ __forceinline__ float fcos_(float x) {          // cos, radians
    float r = x * 0.15915494309f;
    r = __builtin_amdgcn_fractf(r);
    return __builtin_amdgcn_cosf(r);
}

// ---------------- k_prep: pad-transpose + border zero + weight packs ----------------
#define NB_TR 1024   // 4 b * 128 h * 2 wtiles
#define NB_BZ 516    // 4*516*64/256
#define NB_WR 288    // 73728/256
#define NB_WPM 36    // 9216/256

__global__ __launch_bounds__(256) void k_prep(
    const float* __restrict__ x,
    const float* __restrict__ w_b, const float* __restrict__ w_c,
    const float* __restrict__ w_p, const float* __restrict__ w_m,
    float* __restrict__ xp, unsigned short* __restrict__ wr8,
    unsigned short* __restrict__ wpm8)
{
    int bi = blockIdx.x;
    int tid = threadIdx.x;
    if (bi < NB_TR) {
        // transpose one (b, h, 64-wide w tile): x[b,c,h,w] -> xp[b,h+1,w+1,c]
        __shared__ float t[64][65];
        int b = bi >> 8;
        int h = (bi >> 1) & 127;
        int w0 = (bi & 1) * 64;
        int lane6 = tid & 63;
        for (int cc = tid >> 6; cc < 64; cc += 4)
            t[cc][lane6] = x[((b * 64 + cc) * 128 + h) * 128 + w0 + lane6];
        __syncthreads();
        for (int wsub = tid >> 6; wsub < 64; wsub += 4)
            xp[((size_t)(b * HP + h + 1) * WP + (w0 + wsub + 1)) * 64 + lane6] = t[lane6][wsub];
        return;
    }
    bi -= NB_TR;
    if (bi < NB_BZ) {
        // zero the padded border of xp
        int idx = bi * 256 + tid;            // < 4*516*64
        int c = idx & 63;
        int tt = idx >> 6;                   // 0..2063
        int b = tt / 516;
        int j = tt % 516;
        int hp, wp;
        if (j < 130)      { hp = 0;       wp = j; }
        else if (j < 260) { hp = 129;     wp = j - 130; }
        else if (j < 388) { hp = j - 259; wp = 0; }
        else              { hp = j - 387; wp = 129; }
        xp[((size_t)(b * HP + hp) * WP + wp) * 64 + c] = 0.f;
        return;
    }
    bi -= NB_BZ;
    if (bi < NB_WR) {
        // main-GEMM A pack: wr8[kk][ot][lane][j] = W[o=ot*16+(lane&15)][k=kk*32+(lane>>4)*8+j]
        int idx = bi * 256 + tid;            // < 73728
        int j    = idx & 7;
        int lane = (idx >> 3) & 63;
        int ot   = (idx >> 9) & 3;
        int kk   = idx >> 11;
        int o  = ot * 16 + (lane & 15);
        int k  = kk * 32 + (lane >> 4) * 8 + j;
        int slot = k >> 6;
        int c    = k & 63;
        float v;
        if (slot < 9) v = w_b[((o * CC + c) * 3 + slot / 3) * 3 + slot % 3];
        else { int n = slot - 9; v = w_c[((o * CC + c) * 3 + n / 3) * 3 + n % 3]; }
        wr8[idx] = f2bf(v);
        return;
    }
    bi -= NB_WR;
    {
        // offset/mask-conv A pack: wpm8[kk][lane][j] = Wpm[ch=lane&15][k=kk*32+(lane>>4)*8+j]
        int idx = bi * 256 + tid;            // < 9216
        if (idx >= NKC * 64 * 8) return;
        int j    = idx & 7;
        int lane = (idx >> 3) & 63;
        int kk   = idx >> 9;                 // 0..17
        int ch = lane & 15;
        int k  = kk * 32 + (lane >> 4) * 8 + j;   // 0..575
        int tap = k >> 6;
        int c   = k & 63;
        float v = 0.f;
        if (ch < 3)       v = w_p[((ch * CC + c) * 3 + tap / 3) * 3 + tap % 3];
        else if (ch < 12) v = w_m[(((ch - 3) * CC + c) * 3 + tap / 3) * 3 + tap % 3];
        wpm8[idx] = f2bf(v);
    }
}

// ---------------- k_main: fused offsets + gather + dual GEMM ----------------
// 512 threads = 8 waves, 32 pixels/block.
// LDS U: two 16-pixel halves; element (k, p16) at 16B-block blk=(k>>3)*16+(p16^((k>>3)&15)),
// ushort offset within block = k&7.
// Record math deduped (round 5): per 16-lane pixel-group, lane cq<9 computes the
// record for sample n=cq; lanes 9..12 compute l/wd/cos(theta)/sin(theta) once.
// Distribution via __shfl (ds_bpermute) — off the VALU critical path.
__global__ __launch_bounds__(512, 4) void k_main(
    const float* __restrict__ xp, const unsigned short* __restrict__ wr8,
    const unsigned short* __restrict__ wpm8,
    const float* __restrict__ w_p,
    const float* __restrict__ b_p, const float* __restrict__ b_m,
    const float* __restrict__ b_b, float* __restrict__ out)
{
    __shared__ unsigned short U8[2 * 18432];   // 73,728 B
    __shared__ float wth[16][9][4];            // f32 theta-channel weights: [cq][tap][e]

    int tid = threadIdx.x;
    int lane = tid & 63;
    int g = tid >> 6;                 // wave 0..7
    int p_sub = lane >> 4;            // 0..3
    int cq = lane & 15;
    int c0 = cq * 4;

    // XCD-aware swizzle (2048 blocks, divisible by 8)
    int bid = blockIdx.x;
    int swz = (bid & 7) * 256 + (bid >> 3);
    int pixBase = swz * PIXT;

    // fill theta-weight table: wth[cq][tap][e] = w_p[ch=2][c=cq*4+e][tap/3][tap%3]
    for (int i = tid; i < 576; i += 512) {
        int cqi = i / 36;
        int rest = i % 36;
        int tap = rest >> 2;
        int e = rest & 3;
        int c = cqi * 4 + e;
        wth[cqi][tap][e] = w_p[((2 * CC + c) * 3 + tap / 3) * 3 + tap % 3];
    }
    __syncthreads();

    int p_local = g * 4 + p_sub;                 // 0..31
    int ph = p_local >> 4;
    int p16 = p_local & 15;
    int pix = pixBase + p_local;
    int b = pix >> 14;
    int h = (pix >> 7) & 127;
    int w = pix & 127;
    const float* xb = xp + (size_t)b * HP * WP * 64;

    // ---- phase 1a: fixed taps -> U slots 0..8 (bf16) + f32 theta partial
    float th = 0.f;
#pragma unroll
    for (int tap = 0; tap < 9; ++tap) {
        int ti = tap / 3, tj = tap % 3;
        float4 xv = *(const float4*)&xb[((h + ti) * WP + (w + tj)) * 64 + c0];
        float4 wt = *(const float4*)&wth[cq][tap][0];
        th += xv.x * wt.x + xv.y * wt.y + xv.z * wt.z + xv.w * wt.w;
        int k = tap * 64 + c0;
        int kqt = k >> 3;
        int blk = kqt * 16 + (p16 ^ (kqt & 15));
        bf16x4 pk;
        pk[0] = (short)f2bf(xv.x); pk[1] = (short)f2bf(xv.y);
        pk[2] = (short)f2bf(xv.z); pk[3] = (short)f2bf(xv.w);
        *(bf16x4*)&U8[ph * 18432 + blk * 8 + (k & 7)] = pk;
    }
    // reduce theta over the 16 lanes (cq) of the pixel-group
    th += __shfl_xor(th, 1);
    th += __shfl_xor(th, 2);
    th += __shfl_xor(th, 4);
    th += __shfl_xor(th, 8);
    __syncthreads();

    // ---- phase 1b: 12-ch offset/mask conv via MFMA on this wave's own 4 pixels.
    int kq = lane >> 4;
    f32x4 ca = {0.f, 0.f, 0.f, 0.f}, cb = {0.f, 0.f, 0.f, 0.f};
    {
        int colp = lane & 3;
        int pabs = g * 4 + colp;
        int phc = g >> 2;
        int p16c = pabs & 15;
        const bf16x8* av = (const bf16x8*)wpm8;
#pragma unroll
        for (int kk = 0; kk < NKC; ++kk) {
            bf16x8 a = av[kk * 64 + lane];
            int kqt = kk * 4 + kq;
            int blk = kqt * 16 + (p16c ^ (kqt & 15));
            bf16x8 bf = *(const bf16x8*)&U8[phc * 18432 + blk * 8];
            if (kk & 1) cb = __builtin_amdgcn_mfma_f32_16x16x32_bf16(a, bf, cb, 0, 0, 0);
            else        ca = __builtin_amdgcn_mfma_f32_16x16x32_bf16(a, bf, ca, 0, 0, 0);
        }
        ca[0] += cb[0]; ca[1] += cb[1]; ca[2] += cb[2]; ca[3] += cb[3];
    }

    // ---- deduped record math ----
    // conv D layout (verified r2/r4): conv[ch] of pixel p lives in lane ((ch>>2)<<4)+p, reg ch&3.
    int base16 = p_sub << 4;
    // mask channel for this lane's sample n=cq: ch = 3+cq (cq<9)
    int chc = (cq < 9) ? (3 + cq) : 3;
    int srcL = ((chc >> 2) << 4) + p_sub;
    float m0 = __shfl(ca[0], srcL);
    float m1 = __shfl(ca[1], srcL);
    float m2 = __shfl(ca[2], srcL);
    float m3 = __shfl(ca[3], srcL);
    int jj = chc & 3;
    float cm = (jj == 0) ? m0 : (jj == 1) ? m1 : (jj == 2) ? m2 : m3;
    float c0v = __shfl(ca[0], p_sub);    // conv[0] (l channel)
    float c1v = __shfl(ca[1], p_sub);    // conv[1] (wd channel)

    float bp0 = b_p[0], bp1 = b_p[1], bp2 = b_p[2];
    float hval = 0.f;
    if (cq == 9)       hval = fsig_(fsin_(c0v + bp0)) * 48.5f + 1.5f;
    else if (cq == 10) hval = fsig_(fsin_(c1v + bp1)) * 48.5f + 1.5f;
    else if (cq == 11) hval = fcos_(fsig_(fsin_(th + bp2)) * 3.1415926f);
    else if (cq == 12) hval = fsin_(fsig_(fsin_(th + bp2)) * 3.1415926f);
    float l  = __shfl(hval, base16 + 9);
    float wd = __shfl(hval, base16 + 10);
    float ct = __shfl(hval, base16 + 11);
    float st = __shfl(hval, base16 + 12);

    // one record per lane (sample n = cq; lanes cq>=9 produce unread garbage)
    unsigned int qpack; float glt, grb, glb, grt;
    {
        int n = (cq < 9) ? cq : 8;
        float mm = fsig_(cm + b_m[n]);
        float pnx = (float)(n / 3 - 1);
        float pny = (float)(n % 3 - 1);
        float px = (float)(h + 1) + (l * (1.f / 3.f)) * pnx;
        float py = (float)(w + 1) + (wd * (1.f / 3.f)) * pny;
        float pxx = px * ct - py * st;
        float pyy = px * st + py * ct;
        float fx = floorf(pxx);
        float fy = floorf(pyy);
        int qltx = min(max((int)fx, 0), HP - 1);
        int qlty = min(max((int)fy, 0), WP - 1);
        int qrbx = min(max((int)fx + 1, 0), HP - 1);
        int qrby = min(max((int)fy + 1, 0), WP - 1);
        float pcx = fminf(fmaxf(pxx, 0.f), (float)(HP - 1));
        float pcy = fminf(fmaxf(pyy, 0.f), (float)(WP - 1));
        float dltx = 1.f + ((float)qltx - pcx);
        float drbx = 1.f - ((float)qrbx - pcx);
        float dlty = 1.f + ((float)qlty - pcy);
        float drby = 1.f - ((float)qrby - pcy);
        glt = dltx * dlty * mm;
        grb = drbx * drby * mm;
        glb = dltx * drby * mm;
        grt = drbx * dlty * mm;
        qpack = (unsigned)qltx | ((unsigned)qlty << 8) |
                ((unsigned)qrbx << 16) | ((unsigned)qrby << 24);
    }

    // ---- phase 1c: deformable gathers -> U slots 9..17
#pragma unroll
    for (int n = 0; n < 9; ++n) {
        unsigned int q = __shfl(qpack, base16 + n);
        float g_lt = __shfl(glt, base16 + n);
        float g_rb = __shfl(grb, base16 + n);
        float g_lb = __shfl(glb, base16 + n);
        float g_rt = __shfl(grt, base16 + n);
        int qltx = q & 255, qlty = (q >> 8) & 255;
        int qrbx = (q >> 16) & 255, qrby = (q >> 24) & 255;
        float4 xlt = *(const float4*)&xb[(qltx * WP + qlty) * 64 + c0];
        float4 xrb = *(const float4*)&xb[(qrbx * WP + qrby) * 64 + c0];
        float4 xlb = *(const float4*)&xb[(qltx * WP + qrby) * 64 + c0];
        float4 xrt = *(const float4*)&xb[(qrbx * WP + qlty) * 64 + c0];
        float v0 = g_lt * xlt.x + g_rb * xrb.x + g_lb * xlb.x + g_rt * xrt.x;
        float v1 = g_lt * xlt.y + g_rb * xrb.y + g_lb * xlb.y + g_rt * xrt.y;
        float v2 = g_lt * xlt.z + g_rb * xrb.z + g_lb * xlb.z + g_rt * xrt.z;
        float v3 = g_lt * xlt.w + g_rb * xrb.w + g_lb * xlb.w + g_rt * xrt.w;
        int k = (9 + n) * 64 + c0;
        int kqt = k >> 3;
        int blk = kqt * 16 + (p16 ^ (kqt & 15));
        bf16x4 pk;
        pk[0] = (short)f2bf(v0); pk[1] = (short)f2bf(v1);
        pk[2] = (short)f2bf(v2); pk[3] = (short)f2bf(v3);
        *(bf16x4*)&U8[ph * 18432 + blk * 8 + (k & 7)] = pk;
    }
    __syncthreads();

    // ---- phase 2: main GEMM, wave (ot=g&3, ph2=g>>2): 16 o x 16 pixels, K=1152
    int ot = g & 3;
    int ph2 = g >> 2;
    int pn = lane & 15;
    f32x4 a0 = {0.f, 0.f, 0.f, 0.f}, a1 = {0.f, 0.f, 0.f, 0.f};
    const bf16x8* wv = (const bf16x8*)wr8;
#pragma unroll
    for (int kk = 0; kk < NKK; ++kk) {
        bf16x8 a = wv[(kk * 4 + ot) * 64 + lane];
        int kqt = kk * 4 + kq;
        int blk = kqt * 16 + (pn ^ (kqt & 15));
        bf16x8 bf = *(const bf16x8*)&U8[ph2 * 18432 + blk * 8];
        if (kk & 1) a1 = __builtin_amdgcn_mfma_f32_16x16x32_bf16(a, bf, a1, 0, 0, 0);
        else        a0 = __builtin_amdgcn_mfma_f32_16x16x32_bf16(a, bf, a0, 0, 0, 0);
    }

    int pix2 = pixBase + ph2 * 16 + pn;
    int bb2 = pix2 >> 14;
    int hw = pix2 & 16383;
#pragma unroll
    for (int r2 = 0; r2 < 4; ++r2) {
        int o = ot * 16 + kq * 4 + r2;
        out[((size_t)(bb2 * 64 + o)) * 16384 + hw] = a0[r2] + a1[r2] + b_b[o];
    }
}

extern "C" void kernel_launch(void* const* d_in, const int* in_sizes, int n_in,
                              void* d_out, int out_size, void* d_ws, size_t ws_size,
                              hipStream_t stream) {
    const float* x   = (const float*)d_in[0];
    const float* w_b = (const float*)d_in[1];
    const float* b_b = (const float*)d_in[2];
    const float* w_p = (const float*)d_in[3];
    const float* b_p = (const float*)d_in[4];
    const float* w_m = (const float*)d_in[5];
    const float* b_m = (const float*)d_in[6];
    const float* w_c = (const float*)d_in[7];
    float* out = (float*)d_out;

    float* ws = (float*)d_ws;
    float* xp = ws + XP_OFF;
    unsigned short* wr8  = (unsigned short*)(ws + WR8_OFF);
    unsigned short* wpm8 = (unsigned short*)(ws + WPM8_OFF);

    k_prep<<<NB_TR + NB_BZ + NB_WR + NB_WPM, 256, 0, stream>>>(
        x, w_b, w_c, w_p, w_m, xp, wr8, wpm8);
    k_main<<<(BB * HH * WW) / PIXT, 512, 0, stream>>>(
        xp, wr8, wpm8, w_p, b_p, b_m, b_b, out);
}